// Round 8
// baseline (241.114 us; speedup 1.0000x reference)
//
#include <hip/hip_runtime.h>
#include <hip/hip_bf16.h>

#define N_NODES 100000
#define E_EDGES 800000
#define LN_EPS 1e-5f

#define P_BLOCKS 256       // partition (sort) blocks = runs
#define EPB 3125           // edges per run (256*3125 = 800000 exact)
#define SLICE 64           // nodes per bucket (bk = dst>>6)
#define NBK 1563           // ceil(100000/64)
#define NBK_PAD 2048       // 4*512 (scan convenience)
#define QCAP 768           // bucket edge capacity (mean 512, sd ~23 -> 11 sigma)
#define CONV_BLOCKS 128
#define CONV_PER_BLOCK 25000   // 3.2M float4 groups of x / 128 convert blocks

typedef __attribute__((ext_vector_type(4))) float f32x4;
typedef __attribute__((ext_vector_type(8))) short short8;

__device__ __forceinline__ unsigned short f2bf(float f) {
    __hip_bfloat16 h = __float2bfloat16(f);
    return *reinterpret_cast<unsigned short*>(&h);
}
__device__ __forceinline__ float bflo(unsigned int u) { return __uint_as_float(u << 16); }
__device__ __forceinline__ float bfhi(unsigned int u) { return __uint_as_float(u & 0xffff0000u); }

// ---- pass 1: LDS counting-sort of edges by 64-node bucket ------------------
// Blocks [0,256): sort 3125 edges each; write block-major sorted u32 records
// + packed (s0|s1<<16) per-bucket offsets. Blocks [256,384): x->bf16 convert;
// block 256 also emits Bt = bf16 [128 out][256 k] concat(Ws,Wn).
// 512 threads/block. No global atomics. 5 barriers.
__global__ __launch_bounds__(512) void part1(
    const float* __restrict__ x, const float* __restrict__ Ws,
    const float* __restrict__ Wn, const int* __restrict__ ei,
    unsigned short* __restrict__ xb, unsigned int* __restrict__ gstore,
    unsigned int* __restrict__ offs32, unsigned short* __restrict__ Bt)
{
    const int t = threadIdx.x, b = blockIdx.x;
    if (b >= P_BLOCKS) {                 // ---- convert blocks ----
        const int cb = b - P_BLOCKS;
        const float4* x4 = reinterpret_cast<const float4*>(x);
        ushort4* xb4 = reinterpret_cast<ushort4*>(xb);
        const int j0 = cb * CONV_PER_BLOCK;
        for (int j = t; j < CONV_PER_BLOCK; j += 512) {
            float4 v = x4[j0 + j];
            ushort4 o;
            o.x = f2bf(v.x); o.y = f2bf(v.y); o.z = f2bf(v.z); o.w = f2bf(v.w);
            xb4[j0 + j] = o;
        }
        if (cb == 0) {                   // weights -> Bt (tiny: 8192 groups)
            const float4* Ws4 = reinterpret_cast<const float4*>(Ws);
            const float4* Wn4 = reinterpret_cast<const float4*>(Wn);
            ushort4* Bt4 = reinterpret_cast<ushort4*>(Bt);
            for (int idx = t; idx < 8192; idx += 512) {
                int n = idx >> 6, g = idx & 63;
                float4 v = (g < 32) ? Ws4[n * 32 + g] : Wn4[n * 32 + (g - 32)];
                ushort4 o;
                o.x = f2bf(v.x); o.y = f2bf(v.y); o.z = f2bf(v.z); o.w = f2bf(v.w);
                Bt4[idx] = o;
            }
        }
        return;
    }
    __shared__ unsigned int sorted_l[EPB];    // 12.5 KB
    __shared__ int hist[NBK_PAD];             // 8 KB (hist -> starts -> ends)
    __shared__ int wsum[8];
    const int lane = t & 63, wid = t >> 6;
    const int e0 = b * EPB;
    for (int i = t; i < NBK_PAD; i += 512) hist[i] = 0;
    __syncthreads();
    for (int i = t; i < EPB; i += 512)         // histogram dst (edges L1/L2-res)
        atomicAdd(&hist[((unsigned)ei[E_EDGES + e0 + i]) >> 6], 1);
    __syncthreads();
    // exclusive scan of 2048 buckets: thread t owns [4t, 4t+4)
    int h[4], s = 0;
#pragma unroll
    for (int k = 0; k < 4; ++k) { h[k] = hist[t * 4 + k]; s += h[k]; }
    int inc = s;                               // wave-inclusive shfl scan
#pragma unroll
    for (int off = 1; off < 64; off <<= 1) {
        int u = __shfl_up(inc, off);
        if (lane >= off) inc += u;
    }
    if (lane == 63) wsum[wid] = inc;
    __syncthreads();
    int wbase = 0;
#pragma unroll
    for (int w = 0; w < 8; ++w) if (w < wid) wbase += wsum[w];
    unsigned st[5];
    st[0] = wbase + inc - s;                   // exclusive prefix of bucket 4t
#pragma unroll
    for (int k = 0; k < 4; ++k) st[k + 1] = st[k] + h[k];
#pragma unroll
    for (int k = 0; k < 4; ++k) {
        int idx = t * 4 + k;
        if (idx < NBK) offs32[b * NBK + idx] = st[k] | (st[k + 1] << 16);
        hist[idx] = (int)st[k];                // in-place starts
    }
    __syncthreads();
    for (int i = t; i < EPB; i += 512) {       // scatter (edges L1/L2-hot)
        unsigned src = (unsigned)ei[e0 + i];
        unsigned dst = (unsigned)ei[E_EDGES + e0 + i];
        int p = atomicAdd(&hist[dst >> 6], 1);
        sorted_l[p] = (src << 6) | (dst & 63u);
    }
    __syncthreads();
    for (int i = t; i < EPB; i += 512)         // coalesced writeback
        gstore[b * EPB + i] = sorted_l[i];
}

// ---- pass 2: single-read stage -> LDS sort -> quad-row register gather ------
// Block b owns nodes [64b, 64b+64). Thread t copies run-t's segment for this
// bucket into LDS ONCE (position via shfl scan of lengths); histogram/scan/
// scatter then run entirely in LDS. Gather: lane = subi(4 edges) x chunk(16B),
// one uint4 wave-load covers 4 neighbor rows. Exact degree.
__global__ __launch_bounds__(256) void agg2(
    const unsigned int* __restrict__ gstore, const unsigned int* __restrict__ offs32,
    const unsigned short* __restrict__ xb, unsigned short* __restrict__ nb)
{
    __shared__ unsigned int stage[QCAP];     // 3 KB
    __shared__ unsigned int sortedq[QCAP];   // 3 KB
    __shared__ int cnt_l[SLICE], run_l[SLICE], qs_l[SLICE + 1];
    __shared__ int wsum[4];
    const int t = threadIdx.x, b = blockIdx.x;
    const int lane = t & 63, wid = t >> 6;
    if (t < SLICE) { cnt_l[t] = 0; run_l[t] = 0; }
    const unsigned int v = offs32[t * NBK + b];    // one load: both bounds
    const int s0 = (int)(v & 0xffffu), len = (int)(v >> 16) - s0;
    int inc = len;                                 // 256-thread shfl scan
#pragma unroll
    for (int off = 1; off < 64; off <<= 1) {
        int u = __shfl_up(inc, off);
        if (lane >= off) inc += u;
    }
    if (lane == 63) wsum[wid] = inc;
    __syncthreads();
    int wbase = 0;
#pragma unroll
    for (int w = 0; w < 4; ++w) if (w < wid) wbase += wsum[w];
    int pos = wbase + inc - len;
    int total = wsum[0] + wsum[1] + wsum[2] + wsum[3];
    if (total > QCAP) total = QCAP;
    const unsigned int* myrun = gstore + t * EPB + s0;
    for (int k = 0; k < len; ++k)                  // the ONLY global rec read
        if (pos + k < QCAP) stage[pos + k] = myrun[k];
    __syncthreads();
    for (int i = t; i < total; i += 256)           // LDS histogram by node
        atomicAdd(&cnt_l[stage[i] & 63u], 1);
    __syncthreads();
    if (t < SLICE) {                               // wave-0 scan of 64 counts
        int ic = cnt_l[t];
        for (int off = 1; off < 64; off <<= 1) {
            int u = __shfl_up(ic, off);
            if (t >= off) ic += u;
        }
        qs_l[t + 1] = ic;
        if (t == 0) qs_l[0] = 0;
    }
    __syncthreads();
    for (int i = t; i < total; i += 256) {         // LDS scatter
        unsigned rec = stage[i];
        int p = qs_l[rec & 63u] + atomicAdd(&run_l[rec & 63u], 1);
        sortedq[p] = rec;
    }
    __syncthreads();
    // gather: wave owns 16 nodes; lane = subi(4 edges) x chunk(16 x 16B)
    const int wave = t >> 6;
    const int subi = lane >> 4, chunk = lane & 15;
    const uint4* x4 = reinterpret_cast<const uint4*>(xb);   // 16 uint4 per row
    for (int ln = wave * 16; ln < wave * 16 + 16; ++ln) {
        const int qb = qs_l[ln], cc = qs_l[ln + 1] - qb;
        float acc[8];
#pragma unroll
        for (int k = 0; k < 8; ++k) acc[k] = 0.f;
        for (int i = 0; i < cc; i += 4) {
            int idx = i + subi;
            if (idx < cc) {                        // quad-uniform branch
                unsigned rec = sortedq[qb + idx];
                uint4 vv = x4[(rec >> 6) * 16 + chunk];
                acc[0] += bflo(vv.x); acc[1] += bfhi(vv.x);
                acc[2] += bflo(vv.y); acc[3] += bfhi(vv.y);
                acc[4] += bflo(vv.z); acc[5] += bfhi(vv.z);
                acc[6] += bflo(vv.w); acc[7] += bfhi(vv.w);
            }
        }
#pragma unroll
        for (int k = 0; k < 8; ++k) {              // sum the 4 subi groups
            acc[k] += __shfl_xor(acc[k], 16);
            acc[k] += __shfl_xor(acc[k], 32);
        }
        const int node = b * SLICE + ln;
        if (subi == 0 && node < N_NODES) {
            float inv = 1.0f / (float)(cc > 1 ? cc : 1);
            uint4 o;
            o.x = ((unsigned)f2bf(acc[1] * inv) << 16) | f2bf(acc[0] * inv);
            o.y = ((unsigned)f2bf(acc[3] * inv) << 16) | f2bf(acc[2] * inv);
            o.z = ((unsigned)f2bf(acc[5] * inv) << 16) | f2bf(acc[4] * inv);
            o.w = ((unsigned)f2bf(acc[7] * inv) << 16) | f2bf(acc[6] * inv);
            reinterpret_cast<uint4*>(nb)[node * 16 + chunk] = o;
        }
    }
}

// ---- MFMA GEMM + bias + ReLU + LayerNorm, LDS-free ------------------------
// Grid 1563 x 256 thr; wave owns 16 rows x 128 cols (one m-tile). B-frags
// stream from Bt (L2-resident 64KB) as short8 loads -> zero LDS -> high TLP.
// A-frag: A[m=lane&15][k=quad*8+j]; C/D: col=lane&15, row=quad*4+reg.
__global__ __launch_bounds__(256) void fused2(
    const unsigned short* __restrict__ xb, const unsigned short* __restrict__ nb,
    const unsigned short* __restrict__ Bt,
    const float* __restrict__ bias, const float* __restrict__ gamma,
    const float* __restrict__ beta, float* __restrict__ out)
{
    const int t = threadIdx.x;
    const int lane = t & 63, wave = t >> 6;
    const int l16 = lane & 15, quad = lane >> 4;
    const int base = blockIdx.x * 64 + wave * 16;
    int row = base + l16;
    if (row >= N_NODES) row = N_NODES - 1;         // tail clamp; store guarded
    float bia[8], gam[8], bet[8];
#pragma unroll
    for (int n = 0; n < 8; ++n) {
        int col = n * 16 + l16;
        bia[n] = bias[col]; gam[n] = gamma[col]; bet[n] = beta[col];
    }
    f32x4 acc[8];
#pragma unroll
    for (int n = 0; n < 8; ++n) acc[n] = (f32x4)0.f;
#pragma unroll
    for (int kstep = 0; kstep < 8; ++kstep) {
        const unsigned short* Asrc = (kstep < 4) ? xb : nb;
        const int koff = (kstep & 3) * 32 + quad * 8;
        short8 a = *reinterpret_cast<const short8*>(Asrc + row * 128 + koff);
#pragma unroll
        for (int n = 0; n < 8; ++n) {
            short8 bb = *reinterpret_cast<const short8*>(
                Bt + (n * 16 + l16) * 256 + kstep * 32 + quad * 8);
            acc[n] = __builtin_amdgcn_mfma_f32_16x16x32_bf16(a, bb, acc[n], 0, 0, 0);
        }
    }
    // epilogue: bias+ReLU+LN; row R's 128 cols live in the 16 lanes of one quad
#pragma unroll
    for (int r = 0; r < 4; ++r) {
        float h[8], s = 0.f, q = 0.f;
#pragma unroll
        for (int n = 0; n < 8; ++n) {
            float v = acc[n][r] + bia[n];
            v = fmaxf(v, 0.f);
            h[n] = v; s += v; q += v * v;
        }
#pragma unroll
        for (int msk = 1; msk <= 8; msk <<= 1) {
            s += __shfl_xor(s, msk);
            q += __shfl_xor(q, msk);
        }
        const float mu = s * (1.f / 128.f);
        const float var = q * (1.f / 128.f) - mu * mu;
        const float rs = rsqrtf(var + LN_EPS);
        const int R = base + quad * 4 + r;
        if (R < N_NODES) {
#pragma unroll
            for (int n = 0; n < 8; ++n)
                out[R * 128 + n * 16 + l16] = (h[n] - mu) * rs * gam[n] + bet[n];
        }
    }
}

extern "C" void kernel_launch(void* const* d_in, const int* in_sizes, int n_in,
                              void* d_out, int out_size, void* d_ws, size_t ws_size,
                              hipStream_t stream) {
    const float* x      = (const float*)d_in[0];
    const int*   ei     = (const int*)d_in[1];
    const float* Wself  = (const float*)d_in[2];
    const float* Wneigh = (const float*)d_in[3];
    const float* bias   = (const float*)d_in[4];
    const float* gamma  = (const float*)d_in[5];
    const float* beta   = (const float*)d_in[6];
    float* out = (float*)d_out;

    // ws layout (~56.1 MB used)
    char* ws = (char*)d_ws;
    unsigned short* xb = (unsigned short*)ws;                       // 25,600,000
    unsigned short* nb = (unsigned short*)(ws + 25600000);          // 25,600,000
    unsigned int* gstore = (unsigned int*)(ws + 51200000);          //  3,200,000
    unsigned int* offs32 = (unsigned int*)(ws + 54400000);          //  1,600,512
    unsigned short* Bt = (unsigned short*)(ws + 56000512);          //     65,536

    part1<<<P_BLOCKS + CONV_BLOCKS, 512, 0, stream>>>(x, Wself, Wneigh, ei,
                                                      xb, gstore, offs32, Bt);
    agg2<<<NBK, 256, 0, stream>>>(gstore, offs32, xb, nb);
    fused2<<<NBK, 256, 0, stream>>>(xb, nb, Bt, bias, gamma, beta, out);
}